// Round 2
// baseline (2997.345 us; speedup 1.0000x reference)
//
#include <hip/hip_runtime.h>
#include <cstdint>
#include <cstddef>

#define NPTS    8192
#define NPT     2048      // NPOINT
#define KNB     32        // NSAMPLE
#define NB      4         // batch
#define DPTS    29        // point feature channels
#define CINP    32        // 3 + 29
#define CO      64        // COUT
#define KS      (KNB*NPT)     // 65536 positions per (b, channel)
#define TELEM   ((size_t)NB*CO*KS)  // 16777216 floats per tensor
#define MCNT    262144.0f     // B*K*S for batch-norm
#define BNEPS   1e-5f

// ---------------------------------------------------------------- FPS
// One block per batch. 1024 threads, 8 points/thread in registers.
// Strict IEEE sub/mul/add to match the reference's ((dx^2+dy^2)+dz^2);
// argmax with lowest-index tie-break (= jnp.argmax first occurrence).
__global__ __launch_bounds__(1024) void fps_kernel(const float* __restrict__ xyz,
                                                   float* __restrict__ out0,
                                                   int* __restrict__ fidx) {
    const int b = blockIdx.x;
    const int t = threadIdx.x;
    const int lane = t & 63;
    const int wid  = t >> 6;
    const float* xb = xyz + (size_t)b * 3 * NPTS;

    float px[8], py[8], pz[8], dist[8];
    const int base = t * 8;
#pragma unroll
    for (int j = 0; j < 8; ++j) {
        px[j] = xb[base + j];
        py[j] = xb[NPTS + base + j];
        pz[j] = xb[2 * NPTS + base + j];
        dist[j] = 1e10f;
    }

    __shared__ float sc[3];     // current centroid coords
    __shared__ float swm[16];   // per-wave maxes

    if (t == 0) {
        sc[0] = px[0]; sc[1] = py[0]; sc[2] = pz[0];
        out0[b * 3 * NPT + 0]       = px[0];
        out0[b * 3 * NPT + NPT]     = py[0];
        out0[b * 3 * NPT + 2*NPT]   = pz[0];
        fidx[b * NPT + 0] = 0;
    }
    __syncthreads();

    for (int i = 1; i < NPT; ++i) {
        const float cx = sc[0], cy = sc[1], cz = sc[2];
        float tb = -1.0f;   // thread-best (max of my current dists)
#pragma unroll
        for (int j = 0; j < 8; ++j) {
            float dx = __fsub_rn(px[j], cx);
            float dy = __fsub_rn(py[j], cy);
            float dz = __fsub_rn(pz[j], cz);
            float d  = __fadd_rn(__fadd_rn(__fmul_rn(dx, dx), __fmul_rn(dy, dy)),
                                 __fmul_rn(dz, dz));
            dist[j] = fminf(dist[j], d);
            tb = fmaxf(tb, dist[j]);
        }
        // wave max
        float wm = tb;
#pragma unroll
        for (int o = 32; o > 0; o >>= 1) wm = fmaxf(wm, __shfl_xor(wm, o, 64));
        if (lane == 0) swm[wid] = wm;
        __syncthreads();
        // every wave redundantly reduces the 16 wave-maxes (no extra barrier)
        float myv = swm[lane & 15];
        float g = myv;
#pragma unroll
        for (int o = 8; o > 0; o >>= 1) g = fmaxf(g, __shfl_xor(g, o, 64));
        const float gmax = g;   // all lanes hold global max
        // winning wave = lowest wave index holding gmax
        unsigned long long wb = __ballot((lane < 16) && (myv == gmax));
        int wwin = __ffsll((long long)wb) - 1;
        if (wid == wwin) {
            unsigned long long lb = __ballot(tb == gmax);
            int lwin = __ffsll((long long)lb) - 1;
            if (lane == lwin) {
                int jj = 0;
#pragma unroll
                for (int j = 7; j >= 0; --j) if (dist[j] == gmax) jj = j;  // first match
                sc[0] = px[jj]; sc[1] = py[jj]; sc[2] = pz[jj];
                out0[b * 3 * NPT + i]         = px[jj];
                out0[b * 3 * NPT + NPT + i]   = py[jj];
                out0[b * 3 * NPT + 2*NPT + i] = pz[jj];
                fidx[b * NPT + i] = base + jj;
            }
        }
        __syncthreads();
    }
}

// ---------------------------------------------------------------- ball query
// One wave per (b, s). 32 smallest in-radius indices (ascending scan +
// ballot compaction), padded with the first hit.
__global__ __launch_bounds__(256) void ballq_kernel(const float* __restrict__ xyz,
                                                    const float* __restrict__ out0,
                                                    int* __restrict__ idx) {
    const int gw   = (blockIdx.x * 256 + threadIdx.x) >> 6;  // 0..8191
    const int lane = threadIdx.x & 63;
    const int b  = gw >> 11;
    const int si = gw & 2047;
    const float* xb = xyz + (size_t)b * 3 * NPTS;

    const float cx = out0[b * 3 * NPT + si];
    const float cy = out0[b * 3 * NPT + NPT + si];
    const float cz = out0[b * 3 * NPT + 2*NPT + si];
    const float csum = __fadd_rn(__fadd_rn(__fmul_rn(cx, cx), __fmul_rn(cy, cy)),
                                 __fmul_rn(cz, cz));
    const float R2 = (float)(0.1 * 0.1);  // 0x3C23D70A — NOT 0.1f*0.1f!

    __shared__ int buf[4][KNB];
    int* mybuf = buf[threadIdx.x >> 6];

    int cnt = 0;
    for (int n0 = 0; n0 < NPTS && cnt < KNB; n0 += 64) {
        const int i = n0 + lane;
        float pxv = xb[i], pyv = xb[NPTS + i], pzv = xb[2 * NPTS + i];
        float ps = __fadd_rn(__fadd_rn(__fmul_rn(pxv, pxv), __fmul_rn(pyv, pyv)),
                             __fmul_rn(pzv, pzv));
        float dot = __fmaf_rn(pzv, cz, __fmaf_rn(pyv, cy, __fmul_rn(pxv, cx)));
        float sqr = __fsub_rn(__fadd_rn(csum, ps), __fadd_rn(dot, dot));
        bool hit = (sqr <= R2);
        unsigned long long m = __ballot(hit);
        int pos = cnt + __popcll(m & ((1ull << lane) - 1ull));
        if (hit && pos < KNB) mybuf[pos] = i;
        cnt += __popcll(m);
    }
    __syncthreads();
    int c = cnt < KNB ? cnt : KNB;
    int first = (cnt > 0) ? mybuf[0] : 0;
    if (lane < KNB) {
        int v = (lane < c) ? mybuf[lane] : first;
        idx[((size_t)gw << 5) + lane] = v;
    }
}

// ---------------------------------------------------------------- proj conv
// Fused gather/concat + conv(32->64) + BN-stats accumulation.
__global__ __launch_bounds__(256) void proj_kernel(const float* __restrict__ xyz,
                                                   const float* __restrict__ points,
                                                   const float* __restrict__ out0,
                                                   const int* __restrict__ idx,
                                                   const float* __restrict__ W,
                                                   float* __restrict__ out,
                                                   float* __restrict__ stats) {
    const int p = blockIdx.x * 256 + threadIdx.x;   // 0..262143
    const int b = p >> 16;
    const int q = p & 65535;       // k*NPT + s
    const int k = q >> 11;
    const int s = q & 2047;
    const int tid = threadIdx.x;

    __shared__ float ssum[CO], ssq[CO];
    if (tid < CO) { ssum[tid] = 0.f; ssq[tid] = 0.f; }
    __syncthreads();

    const int j = idx[((size_t)(b * NPT + s) << 5) + k];
    const float* xb = xyz + (size_t)b * 3 * NPTS;
    float a[CINP];
    a[0] = xb[j]            - out0[b * 3 * NPT + s];
    a[1] = xb[NPTS + j]     - out0[b * 3 * NPT + NPT + s];
    a[2] = xb[2*NPTS + j]   - out0[b * 3 * NPT + 2*NPT + s];
    const float* pb = points + (size_t)b * DPTS * NPTS;
#pragma unroll
    for (int c = 0; c < DPTS; ++c) a[3 + c] = pb[c * NPTS + j];

    const size_t obase = (size_t)b * CO * KS + q;
    for (int o = 0; o < CO; ++o) {
        float acc = 0.f;
#pragma unroll
        for (int c = 0; c < CINP; ++c) acc = __fmaf_rn(W[o * CINP + c], a[c], acc);
        out[obase + (size_t)o * KS] = acc;
        float s1 = acc, s2 = acc * acc;
#pragma unroll
        for (int off = 32; off > 0; off >>= 1) {
            s1 += __shfl_xor(s1, off, 64);
            s2 += __shfl_xor(s2, off, 64);
        }
        if ((tid & 63) == 0) { atomicAdd(&ssum[o], s1); atomicAdd(&ssq[o], s2); }
    }
    __syncthreads();
    if (tid < CO) {
        atomicAdd(&stats[tid], ssum[tid]);
        atomicAdd(&stats[CO + tid], ssq[tid]);
    }
}

// ---------------------------------------------------------------- fused conv
// input-BN (+optional residual) + relu -> GEMM 64x64 -> raw out + stats.
// NOTE: in/idn/act_out/out may ALIAS (in-place use): no __restrict__ on them.
// Safe because each thread touches only its own q-column {base + i*KS}, and
// all its loads (loop 1) precede all its stores of loop 2 in program order.
template <bool HAS_IDN, bool WRITE_ACT>
__global__ __launch_bounds__(256) void conv_bn_kernel(const float* in,
                                                      const float* idn,
                                                      const float* __restrict__ stats_in,
                                                      const float* __restrict__ gamma,
                                                      const float* __restrict__ beta,
                                                      const float* __restrict__ W,
                                                      float* act_out,
                                                      float* out,
                                                      float* __restrict__ stats_out) {
    const int p = blockIdx.x * 256 + threadIdx.x;
    const int b = p >> 16;
    const int q = p & 65535;
    const int tid = threadIdx.x;

    __shared__ float ssc[CO], ssh[CO], ssum[CO], ssq[CO];
    if (tid < CO) {
        const float Minv = 1.0f / MCNT;
        float m = stats_in[tid] * Minv;
        float v = stats_in[CO + tid] * Minv - m * m;
        float scl = gamma[tid] * rsqrtf(v + BNEPS);
        ssc[tid] = scl;
        ssh[tid] = beta[tid] - m * scl;
        ssum[tid] = 0.f; ssq[tid] = 0.f;
    }
    __syncthreads();

    const size_t base = (size_t)b * CO * KS + q;
    float a[CO];
#pragma unroll
    for (int c = 0; c < CO; ++c) {
        float v = __fmaf_rn(ssc[c], in[base + (size_t)c * KS], ssh[c]);
        if (HAS_IDN) v += idn[base + (size_t)c * KS];
        v = fmaxf(v, 0.0f);
        a[c] = v;
        if (WRITE_ACT) act_out[base + (size_t)c * KS] = v;
    }
    for (int o = 0; o < CO; ++o) {
        float acc = 0.f;
#pragma unroll
        for (int c = 0; c < CO; ++c) acc = __fmaf_rn(W[o * CO + c], a[c], acc);
        out[base + (size_t)o * KS] = acc;
        float s1 = acc, s2 = acc * acc;
#pragma unroll
        for (int off = 32; off > 0; off >>= 1) {
            s1 += __shfl_xor(s1, off, 64);
            s2 += __shfl_xor(s2, off, 64);
        }
        if ((tid & 63) == 0) { atomicAdd(&ssum[o], s1); atomicAdd(&ssq[o], s2); }
    }
    __syncthreads();
    if (tid < CO) {
        atomicAdd(&stats_out[tid], ssum[tid]);
        atomicAdd(&stats_out[CO + tid], ssq[tid]);
    }
}

// ---------------------------------------------------------------- final
// BN + residual + relu + maxpool over k.
__global__ __launch_bounds__(256) void final_kernel(const float* __restrict__ y2,
                                                    const float* __restrict__ idn,
                                                    const float* __restrict__ stats,
                                                    const float* __restrict__ gamma,
                                                    const float* __restrict__ beta,
                                                    float* __restrict__ feat) {
    const int p = blockIdx.x * 256 + threadIdx.x;   // 0..524287
    const int s = p & 2047;
    const int o = (p >> 11) & 63;
    const int b = p >> 17;
    const float Minv = 1.0f / MCNT;
    float m = stats[o] * Minv;
    float v = stats[CO + o] * Minv - m * m;
    float scl = gamma[o] * rsqrtf(v + BNEPS);
    float sh  = beta[o] - m * scl;
    const size_t base = (size_t)b * CO * KS + (size_t)o * KS + s;
    float mx = -1e30f;
#pragma unroll
    for (int k = 0; k < KNB; ++k) {
        float val = __fmaf_rn(scl, y2[base + (size_t)k * NPT], sh) + idn[base + (size_t)k * NPT];
        val = fmaxf(val, 0.0f);
        mx = fmaxf(mx, val);
    }
    feat[p] = mx;
}

__global__ void zero_kernel(float* p, int n) {
    int i = blockIdx.x * blockDim.x + threadIdx.x;
    if (i < n) p[i] = 0.f;
}

extern "C" void kernel_launch(void* const* d_in, const int* in_sizes, int n_in,
                              void* d_out, int out_size, void* d_ws, size_t ws_size,
                              hipStream_t stream) {
    (void)in_sizes; (void)n_in; (void)out_size; (void)ws_size;
    const float* xyz    = (const float*)d_in[0];
    const float* points = (const float*)d_in[1];
    const float* proj_w = (const float*)d_in[2];
    const float* proj_g = (const float*)d_in[3];
    const float* proj_b = (const float*)d_in[4];
    const float* w1     = (const float*)d_in[5];   // (2,64,64)
    const float* g1     = (const float*)d_in[6];
    const float* b1     = (const float*)d_in[7];
    const float* w2     = (const float*)d_in[8];
    const float* g2     = (const float*)d_in[9];
    const float* b2     = (const float*)d_in[10];

    float* out0 = (float*)d_out;                   // (4,3,2048)
    float* feat = (float*)d_out + NB * 3 * NPT;    // (4,64,2048)

    // Workspace layout: small arrays first, then TWO big tensors (A, B).
    // Total: (1024 + 8192 + 262144 + 2*16777216) * 4 B = 135.3 MB.
    float* stats = (float*)d_ws;                    // 5 x 128 (rounded to 1024)
    int*   fidx  = (int*)((float*)d_ws + 1024);     // (4,2048)
    int*   idx   = fidx + NB * NPT;                 // (4,2048,32)
    float* A     = (float*)(idx + NB * NPT * KNB);  // activation tensor
    float* B     = A + TELEM;                       // residual tensor

    hipLaunchKernelGGL(zero_kernel, dim3(3), dim3(256), 0, stream, stats, 5 * 2 * CO);
    hipLaunchKernelGGL(fps_kernel, dim3(NB), dim3(1024), 0, stream, xyz, out0, fidx);
    hipLaunchKernelGGL(ballq_kernel, dim3(2048), dim3(256), 0, stream, xyz, out0, idx);
    // proj raw conv -> A, stats0
    hipLaunchKernelGGL(proj_kernel, dim3(1024), dim3(256), 0, stream,
                       xyz, points, out0, idx, proj_w, A, stats);
    // d=0: x = relu(bnP(A)); idn0 -> B; y1 -> A (in-place)
    hipLaunchKernelGGL((conv_bn_kernel<false, true>), dim3(1024), dim3(256), 0, stream,
                       A, (const float*)nullptr, stats, proj_g, proj_b, w1,
                       B, A, stats + 128);
    // d=0: y2 = conv(w2[0], relu(bn1(y1)))  A -> A
    hipLaunchKernelGGL((conv_bn_kernel<false, false>), dim3(1024), dim3(256), 0, stream,
                       A, (const float*)nullptr, stats + 128, g1, b1, w2,
                       (float*)nullptr, A, stats + 256);
    // d=1: x = relu(bn2(y2)+idn0); idn1 -> B (aliases idn read); y1 -> A
    hipLaunchKernelGGL((conv_bn_kernel<true, true>), dim3(1024), dim3(256), 0, stream,
                       A, B, stats + 256, g2, b2, w1 + CO * CO,
                       B, A, stats + 384);
    // d=1: y2 = conv(w2[1], relu(bn1'(y1)))  A -> A
    hipLaunchKernelGGL((conv_bn_kernel<false, false>), dim3(1024), dim3(256), 0, stream,
                       A, (const float*)nullptr, stats + 384, g1 + CO, b1 + CO, w2 + CO * CO,
                       (float*)nullptr, A, stats + 512);
    // feat = max_k relu(bn2'(A)+B)
    hipLaunchKernelGGL(final_kernel, dim3(2048), dim3(256), 0, stream,
                       A, B, stats + 512, g2 + CO, b2 + CO, feat);
}